// Round 8
// baseline (695.107 us; speedup 1.0000x reference)
//
#include <hip/hip_runtime.h>

constexpr int NN = 50000;   // nodes
constexpr int NE = 800000;  // edges (without self loops)
constexpr int SNB = (NN + 255) / 256;  // scan blocks = 196

typedef _Float16 h8 __attribute__((ext_vector_type(8)));
typedef _Float16 h4v __attribute__((ext_vector_type(4)));
typedef float f32x4 __attribute__((ext_vector_type(4)));

// ----------------------------- CSR build -----------------------------------
__global__ void hist_kernel(const int* __restrict__ dst, int* __restrict__ deg) {
    int e = blockIdx.x * blockDim.x + threadIdx.x;
    if (e < NE) atomicAdd(&deg[dst[e]], 1);
}

__global__ __launch_bounds__(256) void scan_bsum_kernel(const int* __restrict__ deg,
                                                        int* __restrict__ bsum) {
    int i = blockIdx.x * 256 + threadIdx.x;
    int v = (i < NN) ? deg[i] : 0;
#pragma unroll
    for (int off = 32; off > 0; off >>= 1) v += __shfl_xor(v, off);
    __shared__ int ws[4];
    if ((threadIdx.x & 63) == 0) ws[threadIdx.x >> 6] = v;
    __syncthreads();
    if (threadIdx.x == 0) bsum[blockIdx.x] = ws[0] + ws[1] + ws[2] + ws[3];
}

__global__ __launch_bounds__(256) void scan_tops_kernel(const int* __restrict__ bsum,
                                                        int* __restrict__ bpre) {
    int tid = threadIdx.x;
    int v = (tid < SNB) ? bsum[tid] : 0;
    int lane = tid & 63, wid = tid >> 6;
    int x = v;
#pragma unroll
    for (int off = 1; off < 64; off <<= 1) {
        int y = __shfl_up(x, off, 64);
        if (lane >= off) x += y;
    }
    __shared__ int wsum[4];
    if (lane == 63) wsum[wid] = x;
    __syncthreads();
    int wpre = 0;
    for (int w = 0; w < wid; w++) wpre += wsum[w];
    if (tid < SNB) bpre[tid] = wpre + x - v;  // exclusive
    if (tid == 0) bpre[SNB] = wsum[0] + wsum[1] + wsum[2] + wsum[3];
}

__global__ __launch_bounds__(256) void scan_final_kernel(const int* __restrict__ deg,
                                                         const int* __restrict__ bpre,
                                                         int* __restrict__ row_ptr,
                                                         int* __restrict__ fillc) {
    int i = blockIdx.x * 256 + threadIdx.x;
    int v = (i < NN) ? deg[i] : 0;
    int lane = threadIdx.x & 63, wid = threadIdx.x >> 6;
    int x = v;
#pragma unroll
    for (int off = 1; off < 64; off <<= 1) {
        int y = __shfl_up(x, off, 64);
        if (lane >= off) x += y;
    }
    __shared__ int wsum[4];
    if (lane == 63) wsum[wid] = x;
    __syncthreads();
    int wpre = 0;
    for (int w = 0; w < wid; w++) wpre += wsum[w];
    int ex = bpre[blockIdx.x] + wpre + x - v;
    if (i < NN) { row_ptr[i] = ex; fillc[i] = ex; }
    if (i == 0) row_ptr[NN] = bpre[SNB];
}

// fillc pre-initialized to row_ptr -> atomic returns absolute slot
__global__ void fill_kernel(const int* __restrict__ src, const int* __restrict__ dst,
                            int* __restrict__ fillc, int* __restrict__ col) {
    int e = blockIdx.x * blockDim.x + threadIdx.x;
    if (e < NE) {
        int d = dst[e];
        int k = atomicAdd(&fillc[d], 1);
        col[k] = src[e];
    }
}

// -------------- prep (conv1 only): xh = fp16(x), t = x@U --------------------
template <int CI>
__global__ __launch_bounds__(256) void prep_kernel(const float* __restrict__ x,
                                                   const float* __restrict__ U,
                                                   _Float16* __restrict__ xh,
                                                   float* __restrict__ t) {
    __shared__ float Us[CI * 4];
    for (int i = threadIdx.x; i < CI * 4; i += 256) Us[i] = U[i];
    __syncthreads();
    int n = blockIdx.x * 256 + threadIdx.x;
    if (n >= NN) return;
    float xr[CI];
    const float4* xv = reinterpret_cast<const float4*>(x + (size_t)n * CI);
#pragma unroll
    for (int q = 0; q < CI / 4; q++) {
        float4 v = xv[q];
        xr[4 * q + 0] = v.x; xr[4 * q + 1] = v.y; xr[4 * q + 2] = v.z; xr[4 * q + 3] = v.w;
    }
    h8* xo = reinterpret_cast<h8*>(xh + (size_t)n * CI);
#pragma unroll
    for (int q = 0; q < CI / 8; q++) {
        h8 hv;
#pragma unroll
        for (int u = 0; u < 8; u++) hv[u] = (_Float16)xr[8 * q + u];
        xo[q] = hv;
    }
    float a0 = 0.f, a1 = 0.f, a2 = 0.f, a3 = 0.f;
#pragma unroll
    for (int k = 0; k < CI; k++) {
        float xk = xr[k];
        a0 = fmaf(xk, Us[k * 4 + 0], a0); a1 = fmaf(xk, Us[k * 4 + 1], a1);
        a2 = fmaf(xk, Us[k * 4 + 2], a2); a3 = fmaf(xk, Us[k * 4 + 3], a3);
    }
    reinterpret_cast<float4*>(t)[n] = make_float4(a0, a1, a2, a3);
}

// --------- phase A: per-edge softmax weights, node-parallel over CSR --------
// 16 lanes per node; dst implicit (= n); t[n] broadcast; qbuf writes sequential
__global__ __launch_bounds__(256) void edgeq_kernel(const int* __restrict__ col,
                                                    const int* __restrict__ row_ptr,
                                                    const float* __restrict__ t,
                                                    const float* __restrict__ cvec,
                                                    h4v* __restrict__ qbuf) {
    int n = blockIdx.x * 16 + (threadIdx.x >> 4);
    if (n >= NN) return;
    int l16 = threadIdx.x & 15;
    float4 cv = *reinterpret_cast<const float4*>(cvec);
    float4 td = reinterpret_cast<const float4*>(t)[n];
    float b0 = cv.x - td.x, b1 = cv.y - td.y, b2 = cv.z - td.z, b3 = cv.w - td.w;
    int beg = row_ptr[n], end = row_ptr[n + 1];
    for (int e = beg + l16; e < end; e += 16) {
        int s = col[e];
        float4 ts = reinterpret_cast<const float4*>(t)[s];
        float d0 = ts.x + b0, d1 = ts.y + b1, d2 = ts.z + b2, d3 = ts.w + b3;
        float mm = fmaxf(fmaxf(d0, d1), fmaxf(d2, d3));
        float q0 = __expf(d0 - mm), q1 = __expf(d1 - mm);
        float q2 = __expf(d2 - mm), q3 = __expf(d3 - mm);
        float is = 1.f / (q0 + q1 + q2 + q3);
        h4v q;
        q[0] = (_Float16)(q0 * is); q[1] = (_Float16)(q1 * is);
        q[2] = (_Float16)(q2 * is); q[3] = (_Float16)(q3 * is);
        qbuf[e] = q;
    }
}

// --------- phase B: 2 waves per node; 128/CI edge-slots x CI channels -------
template <int CI>
__global__ __launch_bounds__(256) void aggC_kernel(const _Float16* __restrict__ xh,
                                                   const h4v* __restrict__ qbuf,
                                                   const float* __restrict__ cvec,
                                                   const int* __restrict__ row_ptr,
                                                   const int* __restrict__ col,
                                                   _Float16* __restrict__ y) {
    constexpr int SLOTS = 128 / CI;
    __shared__ float part[2][CI * 4];
    int tid = threadIdx.x;
    int half = tid >> 7;            // node within block (0..1)
    int lt = tid & 127;
    int n = blockIdx.x * 2 + half;  // grid = NN/2 exactly
    int ch = lt & (CI - 1);
    int slot = lt / CI;             // 0..SLOTS-1
    float4 cv = *reinterpret_cast<const float4*>(cvec);
    float a0 = 0.f, a1 = 0.f, a2 = 0.f, a3 = 0.f;
    if (slot == 0) {
        float m = fmaxf(fmaxf(cv.x, cv.y), fmaxf(cv.z, cv.w));
        float s0 = __expf(cv.x - m), s1 = __expf(cv.y - m),
              s2 = __expf(cv.z - m), s3 = __expf(cv.w - m);
        float sinv = 1.f / (s0 + s1 + s2 + s3);
        float xself = (float)xh[(size_t)n * CI + ch];
        a0 = s0 * sinv * xself; a1 = s1 * sinv * xself;
        a2 = s2 * sinv * xself; a3 = s3 * sinv * xself;
    }
    int beg = row_ptr[n], end = row_ptr[n + 1];
#pragma unroll 4
    for (int e = beg + slot; e < end; e += SLOTS) {
        int s = col[e];                 // uniform in lane-group -> broadcast
        h4v q = qbuf[e];                // broadcast
        float xv = (float)xh[(size_t)s * CI + ch];
        a0 = fmaf((float)q[0], xv, a0); a1 = fmaf((float)q[1], xv, a1);
        a2 = fmaf((float)q[2], xv, a2); a3 = fmaf((float)q[3], xv, a3);
    }
#pragma unroll
    for (int off = 32; off >= CI; off >>= 1) {
        a0 += __shfl_xor(a0, off); a1 += __shfl_xor(a1, off);
        a2 += __shfl_xor(a2, off); a3 += __shfl_xor(a3, off);
    }
    if (lt >= 64 && lt < 64 + CI) {
        part[half][ch * 4 + 0] = a0; part[half][ch * 4 + 1] = a1;
        part[half][ch * 4 + 2] = a2; part[half][ch * 4 + 3] = a3;
    }
    __syncthreads();
    if (lt < CI) {
        a0 += part[half][ch * 4 + 0]; a1 += part[half][ch * 4 + 1];
        a2 += part[half][ch * 4 + 2]; a3 += part[half][ch * 4 + 3];
        float sc = 1.f / (float)(end - beg + 1);
        _Float16* yo = y + (size_t)n * 4 * CI + ch;
        yo[0]      = (_Float16)(a0 * sc);
        yo[CI]     = (_Float16)(a1 * sc);
        yo[2 * CI] = (_Float16)(a2 * sc);
        yo[3 * CI] = (_Float16)(a3 * sc);
    }
}

// ---------------- MFMA GEMM: out = relu(A @ B + bias) [+ t = out@U] ---------
// v_mfma_f32_16x16x16f16 fragments: A: row=l&15, k=4*(l>>4)+j
//                                   B: col=l&15, k=4*(l>>4)+j
//                                   C: row=(l>>4)*4+i, col=l&15
template <int K, int CO, int COB, bool STACKED, bool OUT16, bool TPREP>
__global__ __launch_bounds__(256) void mfma_dense_kernel(const _Float16* __restrict__ A,
                                                         const float* __restrict__ W,
                                                         const float* __restrict__ bias,
                                                         const float* __restrict__ U,
                                                         void* __restrict__ outp,
                                                         float* __restrict__ tout) {
    constexpr int KS = K / 16;
    constexpr int OT = COB / 16;
    constexpr int CIc = K / 4;
    __shared__ _Float16 Bf[OT * KS * 64 * 4];
    __shared__ float bS[COB];
    __shared__ float Us[TPREP ? CO * 4 : 4];
    int o0 = blockIdx.y * COB;
    for (int idx = threadIdx.x; idx < OT * KS * 64; idx += 256) {
        int lane = idx & 63;
        int ks = (idx >> 6) % KS;
        int ot = idx / (64 * KS);
        int o = o0 + ot * 16 + (lane & 15);
        int kb = ks * 16 + (lane >> 4) * 4;
        h4v v;
#pragma unroll
        for (int j = 0; j < 4; j++) {
            int k = kb + j;
            float wv;
            if constexpr (STACKED) wv = W[(k % CIc) * (4 * CO) + (k / CIc) * CO + o];
            else                   wv = W[k * CO + o];
            v[j] = (_Float16)wv;
        }
        *reinterpret_cast<h4v*>(&Bf[idx * 4]) = v;
    }
    for (int i = threadIdx.x; i < COB; i += 256) bS[i] = bias[o0 + i];
    if constexpr (TPREP) {
        for (int i = threadIdx.x; i < CO * 4; i += 256) Us[i] = U[i];
    }
    __syncthreads();
    int wid = threadIdx.x >> 6, lane = threadIdx.x & 63;
    int row_in = lane & 15;
    int kgrp = lane >> 4;
    for (int mt = blockIdx.x * 4 + wid; mt < NN / 16; mt += gridDim.x * 4) {
        int m0 = mt * 16;
        f32x4 acc[OT];
#pragma unroll
        for (int t = 0; t < OT; t++) acc[t] = {0.f, 0.f, 0.f, 0.f};
        const _Float16* Ab = A + (size_t)(m0 + row_in) * K + kgrp * 4;
#pragma unroll
        for (int ks = 0; ks < KS; ks++) {
            h4v af = *reinterpret_cast<const h4v*>(Ab + ks * 16);
#pragma unroll
            for (int t = 0; t < OT; t++) {
                h4v bf = *reinterpret_cast<const h4v*>(&Bf[((t * KS + ks) * 64 + lane) * 4]);
                acc[t] = __builtin_amdgcn_mfma_f32_16x16x16f16(af, bf, acc[t], 0, 0, 0);
            }
        }
        int orow0 = m0 + kgrp * 4;
#pragma unroll
        for (int t = 0; t < OT; t++) {
            int colo = o0 + t * 16 + row_in;
            float b = bS[t * 16 + row_in];
#pragma unroll
            for (int i = 0; i < 4; i++) {
                float v = fmaxf(acc[t][i] + b, 0.f);
                acc[t][i] = v;   // keep relu'd value for TPREP epilogue
                if constexpr (OUT16)
                    ((_Float16*)outp)[(size_t)(orow0 + i) * CO + colo] = (_Float16)v;
                else
                    ((float*)outp)[(size_t)(orow0 + i) * CO + colo] = v;
            }
        }
        if constexpr (TPREP) {
            // t[row][h] = sum_c out[row][c] * U[c][h]; cols are spread over the
            // 16 lanes of this kgrp group (c = tt*16 + row_in) -> butterfly sum.
            float p[4][4];
#pragma unroll
            for (int i = 0; i < 4; i++)
#pragma unroll
                for (int h = 0; h < 4; h++) p[i][h] = 0.f;
#pragma unroll
            for (int tt = 0; tt < OT; tt++) {
                const float* ur = &Us[(tt * 16 + row_in) * 4];
#pragma unroll
                for (int i = 0; i < 4; i++) {
                    float v = acc[tt][i];
#pragma unroll
                    for (int h = 0; h < 4; h++) p[i][h] = fmaf(v, ur[h], p[i][h]);
                }
            }
#pragma unroll
            for (int mask = 1; mask < 16; mask <<= 1) {
#pragma unroll
                for (int i = 0; i < 4; i++)
#pragma unroll
                    for (int h = 0; h < 4; h++) p[i][h] += __shfl_xor(p[i][h], mask);
            }
            // lane j (=row_in) writes t[orow0 + (j>>2)][j&3]
            tout[(size_t)(orow0 + (row_in >> 2)) * 4 + (row_in & 3)] = p[row_in >> 2][row_in & 3];
        }
    }
}

// ------------------------------- batch norm ---------------------------------
template <int C>
__global__ __launch_bounds__(256) void bn_reduce_kernel(const float* __restrict__ a,
                                                        float* __restrict__ stats) {
    constexpr int R = 256 / C;
    int cidx = threadIdx.x % C;
    int r = threadIdx.x / C;
    float s = 0.f, s2 = 0.f;
    for (int n = blockIdx.x * R + r; n < NN; n += gridDim.x * R) {
        float v = a[(size_t)n * C + cidx];
        s += v; s2 = fmaf(v, v, s2);
    }
    __shared__ float ls[256], ls2[256];
    ls[threadIdx.x] = s; ls2[threadIdx.x] = s2;
    __syncthreads();
    for (int off = 128; off >= C; off >>= 1) {
        if (threadIdx.x < off) {
            ls[threadIdx.x] += ls[threadIdx.x + off];
            ls2[threadIdx.x] += ls2[threadIdx.x + off];
        }
        __syncthreads();
    }
    if (threadIdx.x < C) {
        atomicAdd(&stats[cidx], ls[threadIdx.x]);
        atomicAdd(&stats[C + cidx], ls2[threadIdx.x]);
    }
}

// BN normalize + emit fp16 xh (no relu) + t = bn@U + zh slice (relu, fp16)
template <int C>
__global__ __launch_bounds__(256) void bn_norm_prep_kernel(const float* __restrict__ a,
                                                           const float* __restrict__ stats,
                                                           const float* __restrict__ g,
                                                           const float* __restrict__ be,
                                                           const float* __restrict__ U,
                                                           _Float16* __restrict__ xh,
                                                           float* __restrict__ t,
                                                           _Float16* __restrict__ zh,
                                                           int zoff) {
    __shared__ float mS[C], sS[C], beS[C], Us[C * 4];
    if (threadIdx.x < C) {
        int c = threadIdx.x;
        float mean = stats[c] * (1.f / NN);
        float var = stats[C + c] * (1.f / NN) - mean * mean;
        mS[c] = mean;
        sS[c] = rsqrtf(fmaxf(var, 0.f) + 1e-5f) * g[c];
        beS[c] = be[c];
    }
    for (int i = threadIdx.x; i < C * 4; i += 256) Us[i] = U[i];
    __syncthreads();
    int n = blockIdx.x * 256 + threadIdx.x;
    if (n >= NN) return;
    const float4* ap = reinterpret_cast<const float4*>(a + (size_t)n * C);
    h8* xo = reinterpret_cast<h8*>(xh + (size_t)n * C);
    h8* zo = reinterpret_cast<h8*>(zh + (size_t)n * 128 + zoff);
    float t0 = 0.f, t1 = 0.f, t2 = 0.f, t3 = 0.f;
#pragma unroll
    for (int q8 = 0; q8 < C / 8; q8++) {
        h8 hv, zv;
#pragma unroll
        for (int q4 = 0; q4 < 2; q4++) {
            int c4 = q8 * 2 + q4;
            float4 v = ap[c4];
            float r0 = (v.x - mS[c4 * 4 + 0]) * sS[c4 * 4 + 0] + beS[c4 * 4 + 0];
            float r1 = (v.y - mS[c4 * 4 + 1]) * sS[c4 * 4 + 1] + beS[c4 * 4 + 1];
            float r2 = (v.z - mS[c4 * 4 + 2]) * sS[c4 * 4 + 2] + beS[c4 * 4 + 2];
            float r3 = (v.w - mS[c4 * 4 + 3]) * sS[c4 * 4 + 3] + beS[c4 * 4 + 3];
            hv[q4 * 4 + 0] = (_Float16)r0; hv[q4 * 4 + 1] = (_Float16)r1;
            hv[q4 * 4 + 2] = (_Float16)r2; hv[q4 * 4 + 3] = (_Float16)r3;
            zv[q4 * 4 + 0] = (_Float16)fmaxf(r0, 0.f); zv[q4 * 4 + 1] = (_Float16)fmaxf(r1, 0.f);
            zv[q4 * 4 + 2] = (_Float16)fmaxf(r2, 0.f); zv[q4 * 4 + 3] = (_Float16)fmaxf(r3, 0.f);
            const float* us;
            us = &Us[(c4 * 4 + 0) * 4];
            t0 = fmaf(r0, us[0], t0); t1 = fmaf(r0, us[1], t1); t2 = fmaf(r0, us[2], t2); t3 = fmaf(r0, us[3], t3);
            us = &Us[(c4 * 4 + 1) * 4];
            t0 = fmaf(r1, us[0], t0); t1 = fmaf(r1, us[1], t1); t2 = fmaf(r1, us[2], t2); t3 = fmaf(r1, us[3], t3);
            us = &Us[(c4 * 4 + 2) * 4];
            t0 = fmaf(r2, us[0], t0); t1 = fmaf(r2, us[1], t1); t2 = fmaf(r2, us[2], t2); t3 = fmaf(r2, us[3], t3);
            us = &Us[(c4 * 4 + 3) * 4];
            t0 = fmaf(r3, us[0], t0); t1 = fmaf(r3, us[1], t1); t2 = fmaf(r3, us[2], t2); t3 = fmaf(r3, us[3], t3);
        }
        xo[q8] = hv;
        zo[q8] = zv;
    }
    reinterpret_cast<float4*>(t)[n] = make_float4(t0, t1, t2, t3);
}

// BN normalize (conv6) -> zh[:, 64:128] = fp16(relu(bn))
template <int C>
__global__ __launch_bounds__(256) void bn_norm_z_kernel(const float* __restrict__ a,
                                                        const float* __restrict__ stats,
                                                        const float* __restrict__ g,
                                                        const float* __restrict__ be,
                                                        _Float16* __restrict__ zh,
                                                        int zoff) {
    __shared__ float mS[C], sS[C], beS[C];
    if (threadIdx.x < C) {
        int c = threadIdx.x;
        float mean = stats[c] * (1.f / NN);
        float var = stats[C + c] * (1.f / NN) - mean * mean;
        mS[c] = mean;
        sS[c] = rsqrtf(fmaxf(var, 0.f) + 1e-5f) * g[c];
        beS[c] = be[c];
    }
    __syncthreads();
    int n = blockIdx.x * 256 + threadIdx.x;
    if (n >= NN) return;
    const float4* ap = reinterpret_cast<const float4*>(a + (size_t)n * C);
    h8* zo = reinterpret_cast<h8*>(zh + (size_t)n * 128 + zoff);
#pragma unroll
    for (int q8 = 0; q8 < C / 8; q8++) {
        h8 zv;
#pragma unroll
        for (int q4 = 0; q4 < 2; q4++) {
            int c4 = q8 * 2 + q4;
            float4 v = ap[c4];
            zv[q4 * 4 + 0] = (_Float16)fmaxf((v.x - mS[c4 * 4 + 0]) * sS[c4 * 4 + 0] + beS[c4 * 4 + 0], 0.f);
            zv[q4 * 4 + 1] = (_Float16)fmaxf((v.y - mS[c4 * 4 + 1]) * sS[c4 * 4 + 1] + beS[c4 * 4 + 1], 0.f);
            zv[q4 * 4 + 2] = (_Float16)fmaxf((v.z - mS[c4 * 4 + 2]) * sS[c4 * 4 + 2] + beS[c4 * 4 + 2], 0.f);
            zv[q4 * 4 + 3] = (_Float16)fmaxf((v.w - mS[c4 * 4 + 3]) * sS[c4 * 4 + 3] + beS[c4 * 4 + 3], 0.f);
        }
        zo[q8] = zv;
    }
}

// ---------------- final: z3 = relu(z2@lw3+lb3); out = sigmoid(z3@lwo+lbo) ---
__global__ __launch_bounds__(256) void lin3o_kernel(const _Float16* __restrict__ z2,
                                                    const float* __restrict__ lw3,
                                                    const float* __restrict__ lb3,
                                                    const float* __restrict__ lwo,
                                                    const float* __restrict__ lbo,
                                                    float* __restrict__ out) {
    __shared__ float W3s[64 * 16];
    __shared__ float Wos[16];
    __shared__ float b3s[16];
    for (int i = threadIdx.x; i < 64 * 16; i += 256) W3s[i] = lw3[i];
    if (threadIdx.x < 16) { Wos[threadIdx.x] = lwo[threadIdx.x]; b3s[threadIdx.x] = lb3[threadIdx.x]; }
    __syncthreads();
    int n = blockIdx.x * 256 + threadIdx.x;
    if (n >= NN) return;
    float acc[16];
#pragma unroll
    for (int u = 0; u < 16; u++) acc[u] = b3s[u];
    const h8* zp = reinterpret_cast<const h8*>(z2 + (size_t)n * 64);
#pragma unroll
    for (int k8 = 0; k8 < 8; k8++) {
        h8 v = zp[k8];
#pragma unroll
        for (int u = 0; u < 8; u++) {
            float vf = (float)v[u];
            const float* w = &W3s[(k8 * 8 + u) * 16];
#pragma unroll
            for (int o = 0; o < 16; o++) acc[o] = fmaf(vf, w[o], acc[o]);
        }
    }
    float s = lbo[0];
#pragma unroll
    for (int u = 0; u < 16; u++) s = fmaf(fmaxf(acc[u], 0.f), Wos[u], s);
    out[n] = 1.f / (1.f + __expf(-s));
}

// ------------------------------- launcher -----------------------------------
extern "C" void kernel_launch(void* const* d_in, const int* in_sizes, int n_in,
                              void* d_out, int out_size, void* d_ws, size_t ws_size,
                              hipStream_t stream) {
    const float* x = (const float*)d_in[0];
    const int* ei = (const int*)d_in[1];
    const int* esrc = ei;
    const int* edst = ei + NE;
    const float* W[6]; const float* U[6]; const float* C[6]; const float* B[6];
    for (int i = 0; i < 6; i++) {
        W[i] = (const float*)d_in[2 + 4 * i];
        U[i] = (const float*)d_in[3 + 4 * i];
        C[i] = (const float*)d_in[4 + 4 * i];
        B[i] = (const float*)d_in[5 + 4 * i];
    }
    const float* g1 = (const float*)d_in[26]; const float* be1 = (const float*)d_in[27];
    const float* g2 = (const float*)d_in[28]; const float* be2 = (const float*)d_in[29];
    const float* g3 = (const float*)d_in[30]; const float* be3 = (const float*)d_in[31];
    const float* lw1 = (const float*)d_in[32]; const float* lb1 = (const float*)d_in[33];
    const float* lw2 = (const float*)d_in[34]; const float* lb2 = (const float*)d_in[35];
    const float* lw3 = (const float*)d_in[36]; const float* lb3 = (const float*)d_in[37];
    const float* lwo = (const float*)d_in[38]; const float* lbo = (const float*)d_in[39];

    char* w = (char*)d_ws;
    size_t o = 0;
    auto take = [&](size_t bytes) -> char* {
        char* p = w + o;
        o = (o + bytes + 255) & ~(size_t)255;
        return p;
    };
    int* deg = (int*)take((size_t)NN * 4);
    float* stats = (float*)take(3 * 256 * 4);
    size_t zero_bytes = o;                    // deg + stats zeroed
    int* fillc = (int*)take((size_t)NN * 4);  // init by scan_final
    int* row_ptr = (int*)take((size_t)(NN + 1) * 4);
    int* bsum = (int*)take((size_t)(SNB + 1) * 4);
    int* bpre = (int*)take((size_t)(SNB + 1) * 4);
    int* colA = (int*)take((size_t)NE * 4);
    h4v* qbuf = (h4v*)take((size_t)NE * 8);
    float* t = (float*)take((size_t)NN * 4 * 4);
    _Float16* xh = (_Float16*)take((size_t)NN * 32 * 2);
    char* A = take((size_t)NN * 256 * 2);     // y fp16 [N,128] then z1h fp16 [N,256]
    _Float16* y = (_Float16*)A;
    _Float16* z1h = (_Float16*)A;
    _Float16* zh = (_Float16*)take((size_t)NN * 128 * 2);
    float* tmp = (float*)take((size_t)NN * 64 * 4);
    _Float16* z2h = (_Float16*)tmp;           // tmp free after bn3
    float* st0 = stats, *st1 = stats + 256, *st2 = stats + 512;

    hipMemsetAsync(d_ws, 0, zero_bytes, stream);

    const int EB = (NE + 255) / 256;
    const int NB = (NN + 255) / 256;
    const int QB = (NN + 15) / 16;             // edgeq blocks (16 nodes/block)
    const int GB = 250;                        // mfma grid.x

    hist_kernel<<<EB, 256, 0, stream>>>(edst, deg);
    scan_bsum_kernel<<<SNB, 256, 0, stream>>>(deg, bsum);
    scan_tops_kernel<<<1, 256, 0, stream>>>(bsum, bpre);
    scan_final_kernel<<<SNB, 256, 0, stream>>>(deg, bpre, row_ptr, fillc);
    fill_kernel<<<EB, 256, 0, stream>>>(esrc, edst, fillc, colA);

    // conv1: 16 -> 16 (mfma emits xh + t via fused epilogue)
    prep_kernel<16><<<NB, 256, 0, stream>>>(x, U[0], xh, t);
    edgeq_kernel<<<QB, 256, 0, stream>>>(colA, row_ptr, t, C[0], qbuf);
    aggC_kernel<16><<<NN / 2, 256, 0, stream>>>(xh, qbuf, C[0], row_ptr, colA, y);
    mfma_dense_kernel<64, 16, 16, true, true, true><<<dim3(GB, 1), 256, 0, stream>>>(y, W[0], B[0], U[1], xh, t);
    // conv2: 16 -> 32, BN1 -> xh/t/zh[:,0:32]
    edgeq_kernel<<<QB, 256, 0, stream>>>(colA, row_ptr, t, C[1], qbuf);
    aggC_kernel<16><<<NN / 2, 256, 0, stream>>>(xh, qbuf, C[1], row_ptr, colA, y);
    mfma_dense_kernel<64, 32, 32, true, false, false><<<dim3(GB, 1), 256, 0, stream>>>(y, W[1], B[1], nullptr, tmp, nullptr);
    bn_reduce_kernel<32><<<256, 256, 0, stream>>>(tmp, st0);
    bn_norm_prep_kernel<32><<<NB, 256, 0, stream>>>(tmp, st0, g1, be1, U[2], xh, t, zh, 0);
    // conv3: 32 -> 32
    edgeq_kernel<<<QB, 256, 0, stream>>>(colA, row_ptr, t, C[2], qbuf);
    aggC_kernel<32><<<NN / 2, 256, 0, stream>>>(xh, qbuf, C[2], row_ptr, colA, y);
    mfma_dense_kernel<128, 32, 32, true, true, true><<<dim3(GB, 1), 256, 0, stream>>>(y, W[2], B[2], U[3], xh, t);
    // conv4: 32 -> 32, BN2 -> xh/t/zh[:,32:64]
    edgeq_kernel<<<QB, 256, 0, stream>>>(colA, row_ptr, t, C[3], qbuf);
    aggC_kernel<32><<<NN / 2, 256, 0, stream>>>(xh, qbuf, C[3], row_ptr, colA, y);
    mfma_dense_kernel<128, 32, 32, true, false, false><<<dim3(GB, 1), 256, 0, stream>>>(y, W[3], B[3], nullptr, tmp, nullptr);
    bn_reduce_kernel<32><<<256, 256, 0, stream>>>(tmp, st1);
    bn_norm_prep_kernel<32><<<NB, 256, 0, stream>>>(tmp, st1, g2, be2, U[4], xh, t, zh, 32);
    // conv5: 32 -> 32
    edgeq_kernel<<<QB, 256, 0, stream>>>(colA, row_ptr, t, C[4], qbuf);
    aggC_kernel<32><<<NN / 2, 256, 0, stream>>>(xh, qbuf, C[4], row_ptr, colA, y);
    mfma_dense_kernel<128, 32, 32, true, true, true><<<dim3(GB, 1), 256, 0, stream>>>(y, W[4], B[4], U[5], xh, t);
    // conv6: 32 -> 64, BN3 -> zh[:,64:128]
    edgeq_kernel<<<QB, 256, 0, stream>>>(colA, row_ptr, t, C[5], qbuf);
    aggC_kernel<32><<<NN / 2, 256, 0, stream>>>(xh, qbuf, C[5], row_ptr, colA, y);
    mfma_dense_kernel<128, 64, 64, true, false, false><<<dim3(GB, 1), 256, 0, stream>>>(y, W[5], B[5], nullptr, tmp, nullptr);
    bn_reduce_kernel<64><<<256, 256, 0, stream>>>(tmp, st2);
    bn_norm_z_kernel<64><<<NB, 256, 0, stream>>>(tmp, st2, g3, be3, zh, 64);

    // MLP head
    mfma_dense_kernel<128, 256, 64, false, true, false><<<dim3(GB, 4), 256, 0, stream>>>(zh, lw1, lb1, nullptr, z1h, nullptr);
    mfma_dense_kernel<256, 64, 64, false, true, false><<<dim3(GB, 1), 256, 0, stream>>>(z1h, lw2, lb2, nullptr, z2h, nullptr);
    lin3o_kernel<<<NB, 256, 0, stream>>>(z2h, lw3, lb3, lwo, lbo, (float*)d_out);
}

// Round 9
// 625.686 us; speedup vs baseline: 1.1110x; 1.1110x over previous
//
#include <hip/hip_runtime.h>

constexpr int NN = 50000;   // nodes
constexpr int NE = 800000;  // edges (without self loops)
constexpr int SNB = (NN + 255) / 256;  // scan blocks = 196

typedef _Float16 h8 __attribute__((ext_vector_type(8)));
typedef _Float16 h4v __attribute__((ext_vector_type(4)));
typedef float f32x4 __attribute__((ext_vector_type(4)));

// ----------------------------- CSR build -----------------------------------
__global__ void hist_kernel(const int* __restrict__ dst, int* __restrict__ deg) {
    int e = blockIdx.x * blockDim.x + threadIdx.x;
    if (e < NE) atomicAdd(&deg[dst[e]], 1);
}

__global__ __launch_bounds__(256) void scan_bsum_kernel(const int* __restrict__ deg,
                                                        int* __restrict__ bsum) {
    int i = blockIdx.x * 256 + threadIdx.x;
    int v = (i < NN) ? deg[i] : 0;
#pragma unroll
    for (int off = 32; off > 0; off >>= 1) v += __shfl_xor(v, off);
    __shared__ int ws[4];
    if ((threadIdx.x & 63) == 0) ws[threadIdx.x >> 6] = v;
    __syncthreads();
    if (threadIdx.x == 0) bsum[blockIdx.x] = ws[0] + ws[1] + ws[2] + ws[3];
}

__global__ __launch_bounds__(256) void scan_tops_kernel(const int* __restrict__ bsum,
                                                        int* __restrict__ bpre) {
    int tid = threadIdx.x;
    int v = (tid < SNB) ? bsum[tid] : 0;
    int lane = tid & 63, wid = tid >> 6;
    int x = v;
#pragma unroll
    for (int off = 1; off < 64; off <<= 1) {
        int y = __shfl_up(x, off, 64);
        if (lane >= off) x += y;
    }
    __shared__ int wsum[4];
    if (lane == 63) wsum[wid] = x;
    __syncthreads();
    int wpre = 0;
    for (int w = 0; w < wid; w++) wpre += wsum[w];
    if (tid < SNB) bpre[tid] = wpre + x - v;  // exclusive
    if (tid == 0) bpre[SNB] = wsum[0] + wsum[1] + wsum[2] + wsum[3];
}

__global__ __launch_bounds__(256) void scan_final_kernel(const int* __restrict__ deg,
                                                         const int* __restrict__ bpre,
                                                         int* __restrict__ row_ptr,
                                                         int* __restrict__ fillc) {
    int i = blockIdx.x * 256 + threadIdx.x;
    int v = (i < NN) ? deg[i] : 0;
    int lane = threadIdx.x & 63, wid = threadIdx.x >> 6;
    int x = v;
#pragma unroll
    for (int off = 1; off < 64; off <<= 1) {
        int y = __shfl_up(x, off, 64);
        if (lane >= off) x += y;
    }
    __shared__ int wsum[4];
    if (lane == 63) wsum[wid] = x;
    __syncthreads();
    int wpre = 0;
    for (int w = 0; w < wid; w++) wpre += wsum[w];
    int ex = bpre[blockIdx.x] + wpre + x - v;
    if (i < NN) { row_ptr[i] = ex; fillc[i] = ex; }
    if (i == 0) row_ptr[NN] = bpre[SNB];
}

// fillc pre-initialized to row_ptr -> atomic returns absolute slot
__global__ void fill_kernel(const int* __restrict__ src, const int* __restrict__ dst,
                            int* __restrict__ fillc, int* __restrict__ col) {
    int e = blockIdx.x * blockDim.x + threadIdx.x;
    if (e < NE) {
        int d = dst[e];
        int k = atomicAdd(&fillc[d], 1);
        col[k] = src[e];
    }
}

// -------------- prep (conv1 only): xh = fp16(x), t = x@U --------------------
template <int CI>
__global__ __launch_bounds__(256) void prep_kernel(const float* __restrict__ x,
                                                   const float* __restrict__ U,
                                                   _Float16* __restrict__ xh,
                                                   float* __restrict__ t) {
    __shared__ float Us[CI * 4];
    for (int i = threadIdx.x; i < CI * 4; i += 256) Us[i] = U[i];
    __syncthreads();
    int n = blockIdx.x * 256 + threadIdx.x;
    if (n >= NN) return;
    float xr[CI];
    const float4* xv = reinterpret_cast<const float4*>(x + (size_t)n * CI);
#pragma unroll
    for (int q = 0; q < CI / 4; q++) {
        float4 v = xv[q];
        xr[4 * q + 0] = v.x; xr[4 * q + 1] = v.y; xr[4 * q + 2] = v.z; xr[4 * q + 3] = v.w;
    }
    h8* xo = reinterpret_cast<h8*>(xh + (size_t)n * CI);
#pragma unroll
    for (int q = 0; q < CI / 8; q++) {
        h8 hv;
#pragma unroll
        for (int u = 0; u < 8; u++) hv[u] = (_Float16)xr[8 * q + u];
        xo[q] = hv;
    }
    float a0 = 0.f, a1 = 0.f, a2 = 0.f, a3 = 0.f;
#pragma unroll
    for (int k = 0; k < CI; k++) {
        float xk = xr[k];
        a0 = fmaf(xk, Us[k * 4 + 0], a0); a1 = fmaf(xk, Us[k * 4 + 1], a1);
        a2 = fmaf(xk, Us[k * 4 + 2], a2); a3 = fmaf(xk, Us[k * 4 + 3], a3);
    }
    reinterpret_cast<float4*>(t)[n] = make_float4(a0, a1, a2, a3);
}

// ------- fused aggregation: q computed once per edge (LDS), then gather -----
// 1 node per 128-thread block. Phase 1: lane j computes softmax q for edge j.
// Phase 2: NSLOT slots x CI channels gather xh and FMA. y[n,h*CI+c] output.
template <int CI>
__global__ __launch_bounds__(128) void aggD_kernel(const _Float16* __restrict__ xh,
                                                   const float* __restrict__ t,
                                                   const float* __restrict__ cvec,
                                                   const int* __restrict__ row_ptr,
                                                   const int* __restrict__ col,
                                                   _Float16* __restrict__ y) {
    constexpr int NSLOT = 128 / CI;
    __shared__ int ss[128];
    __shared__ float4 qs[128];
    __shared__ float part[CI * 4];
    int tid = threadIdx.x;
    int n = blockIdx.x;                  // grid = NN exactly
    int ch = tid & (CI - 1);
    int slot = tid / CI;
    float4 cv = *reinterpret_cast<const float4*>(cvec);
    float4 td = reinterpret_cast<const float4*>(t)[n];
    float b0 = cv.x - td.x, b1 = cv.y - td.y, b2 = cv.z - td.z, b3 = cv.w - td.w;
    float a0 = 0.f, a1 = 0.f, a2 = 0.f, a3 = 0.f;
    if (slot == 0) {   // self loop: q = softmax(c)
        float m = fmaxf(fmaxf(cv.x, cv.y), fmaxf(cv.z, cv.w));
        float s0 = __expf(cv.x - m), s1 = __expf(cv.y - m),
              s2 = __expf(cv.z - m), s3 = __expf(cv.w - m);
        float sinv = 1.f / (s0 + s1 + s2 + s3);
        float xself = (float)xh[(size_t)n * CI + ch];
        a0 = s0 * sinv * xself; a1 = s1 * sinv * xself;
        a2 = s2 * sinv * xself; a3 = s3 * sinv * xself;
    }
    int beg = row_ptr[n], end = row_ptr[n + 1];
    for (int base = beg; base < end; base += 128) {
        int m = end - base;
        if (m > 128) m = 128;
        if (tid < m) {
            int s = col[base + tid];
            float4 ts = reinterpret_cast<const float4*>(t)[s];
            float d0 = ts.x + b0, d1 = ts.y + b1, d2 = ts.z + b2, d3 = ts.w + b3;
            float mm = fmaxf(fmaxf(d0, d1), fmaxf(d2, d3));
            float q0 = __expf(d0 - mm), q1 = __expf(d1 - mm);
            float q2 = __expf(d2 - mm), q3 = __expf(d3 - mm);
            float is = 1.f / (q0 + q1 + q2 + q3);
            ss[tid] = s;
            qs[tid] = make_float4(q0 * is, q1 * is, q2 * is, q3 * is);
        }
        __syncthreads();
#pragma unroll 4
        for (int j = slot; j < m; j += NSLOT) {
            int s = ss[j];                  // LDS broadcast within lane group
            float4 q = qs[j];
            float xv = (float)xh[(size_t)s * CI + ch];
            a0 = fmaf(q.x, xv, a0); a1 = fmaf(q.y, xv, a1);
            a2 = fmaf(q.z, xv, a2); a3 = fmaf(q.w, xv, a3);
        }
        __syncthreads();                    // protect LDS before next chunk
    }
    // combine slots: intra-wave butterfly, then cross-wave via LDS
#pragma unroll
    for (int off = 32; off >= CI; off >>= 1) {
        a0 += __shfl_xor(a0, off); a1 += __shfl_xor(a1, off);
        a2 += __shfl_xor(a2, off); a3 += __shfl_xor(a3, off);
    }
    if (tid >= 64 && tid < 64 + CI) {
        part[ch * 4 + 0] = a0; part[ch * 4 + 1] = a1;
        part[ch * 4 + 2] = a2; part[ch * 4 + 3] = a3;
    }
    __syncthreads();
    if (tid < CI) {
        a0 += part[ch * 4 + 0]; a1 += part[ch * 4 + 1];
        a2 += part[ch * 4 + 2]; a3 += part[ch * 4 + 3];
        float sc = 1.f / (float)(end - beg + 1);
        _Float16* yo = y + (size_t)n * 4 * CI + ch;
        yo[0]      = (_Float16)(a0 * sc);
        yo[CI]     = (_Float16)(a1 * sc);
        yo[2 * CI] = (_Float16)(a2 * sc);
        yo[3 * CI] = (_Float16)(a3 * sc);
    }
}

// ---------------- MFMA GEMM: out = relu(A @ B + bias) [+ t = out@U] ---------
// v_mfma_f32_16x16x16f16 fragments: A: row=l&15, k=4*(l>>4)+j
//                                   B: col=l&15, k=4*(l>>4)+j
//                                   C: row=(l>>4)*4+i, col=l&15
template <int K, int CO, int COB, bool STACKED, bool OUT16, bool TPREP>
__global__ __launch_bounds__(256) void mfma_dense_kernel(const _Float16* __restrict__ A,
                                                         const float* __restrict__ W,
                                                         const float* __restrict__ bias,
                                                         const float* __restrict__ U,
                                                         void* __restrict__ outp,
                                                         float* __restrict__ tout) {
    constexpr int KS = K / 16;
    constexpr int OT = COB / 16;
    constexpr int CIc = K / 4;
    __shared__ _Float16 Bf[OT * KS * 64 * 4];
    __shared__ float bS[COB];
    __shared__ float Us[TPREP ? CO * 4 : 4];
    int o0 = blockIdx.y * COB;
    for (int idx = threadIdx.x; idx < OT * KS * 64; idx += 256) {
        int lane = idx & 63;
        int ks = (idx >> 6) % KS;
        int ot = idx / (64 * KS);
        int o = o0 + ot * 16 + (lane & 15);
        int kb = ks * 16 + (lane >> 4) * 4;
        h4v v;
#pragma unroll
        for (int j = 0; j < 4; j++) {
            int k = kb + j;
            float wv;
            if constexpr (STACKED) wv = W[(k % CIc) * (4 * CO) + (k / CIc) * CO + o];
            else                   wv = W[k * CO + o];
            v[j] = (_Float16)wv;
        }
        *reinterpret_cast<h4v*>(&Bf[idx * 4]) = v;
    }
    for (int i = threadIdx.x; i < COB; i += 256) bS[i] = bias[o0 + i];
    if constexpr (TPREP) {
        for (int i = threadIdx.x; i < CO * 4; i += 256) Us[i] = U[i];
    }
    __syncthreads();
    int wid = threadIdx.x >> 6, lane = threadIdx.x & 63;
    int row_in = lane & 15;
    int kgrp = lane >> 4;
    for (int mt = blockIdx.x * 4 + wid; mt < NN / 16; mt += gridDim.x * 4) {
        int m0 = mt * 16;
        f32x4 acc[OT];
#pragma unroll
        for (int t = 0; t < OT; t++) acc[t] = {0.f, 0.f, 0.f, 0.f};
        const _Float16* Ab = A + (size_t)(m0 + row_in) * K + kgrp * 4;
#pragma unroll
        for (int ks = 0; ks < KS; ks++) {
            h4v af = *reinterpret_cast<const h4v*>(Ab + ks * 16);
#pragma unroll
            for (int t = 0; t < OT; t++) {
                h4v bf = *reinterpret_cast<const h4v*>(&Bf[((t * KS + ks) * 64 + lane) * 4]);
                acc[t] = __builtin_amdgcn_mfma_f32_16x16x16f16(af, bf, acc[t], 0, 0, 0);
            }
        }
        int orow0 = m0 + kgrp * 4;
#pragma unroll
        for (int t = 0; t < OT; t++) {
            int colo = o0 + t * 16 + row_in;
            float b = bS[t * 16 + row_in];
#pragma unroll
            for (int i = 0; i < 4; i++) {
                float v = fmaxf(acc[t][i] + b, 0.f);
                acc[t][i] = v;   // keep relu'd value for TPREP epilogue
                if constexpr (OUT16)
                    ((_Float16*)outp)[(size_t)(orow0 + i) * CO + colo] = (_Float16)v;
                else
                    ((float*)outp)[(size_t)(orow0 + i) * CO + colo] = v;
            }
        }
        if constexpr (TPREP) {
            float p[4][4];
#pragma unroll
            for (int i = 0; i < 4; i++)
#pragma unroll
                for (int h = 0; h < 4; h++) p[i][h] = 0.f;
#pragma unroll
            for (int tt = 0; tt < OT; tt++) {
                const float* ur = &Us[(tt * 16 + row_in) * 4];
#pragma unroll
                for (int i = 0; i < 4; i++) {
                    float v = acc[tt][i];
#pragma unroll
                    for (int h = 0; h < 4; h++) p[i][h] = fmaf(v, ur[h], p[i][h]);
                }
            }
#pragma unroll
            for (int mask = 1; mask < 16; mask <<= 1) {
#pragma unroll
                for (int i = 0; i < 4; i++)
#pragma unroll
                    for (int h = 0; h < 4; h++) p[i][h] += __shfl_xor(p[i][h], mask);
            }
            tout[(size_t)(orow0 + (row_in >> 2)) * 4 + (row_in & 3)] = p[row_in >> 2][row_in & 3];
        }
    }
}

// ------------------------------- batch norm ---------------------------------
template <int C>
__global__ __launch_bounds__(256) void bn_reduce_kernel(const float* __restrict__ a,
                                                        float* __restrict__ stats) {
    constexpr int R = 256 / C;
    int cidx = threadIdx.x % C;
    int r = threadIdx.x / C;
    float s = 0.f, s2 = 0.f;
    for (int n = blockIdx.x * R + r; n < NN; n += gridDim.x * R) {
        float v = a[(size_t)n * C + cidx];
        s += v; s2 = fmaf(v, v, s2);
    }
    __shared__ float ls[256], ls2[256];
    ls[threadIdx.x] = s; ls2[threadIdx.x] = s2;
    __syncthreads();
    for (int off = 128; off >= C; off >>= 1) {
        if (threadIdx.x < off) {
            ls[threadIdx.x] += ls[threadIdx.x + off];
            ls2[threadIdx.x] += ls2[threadIdx.x + off];
        }
        __syncthreads();
    }
    if (threadIdx.x < C) {
        atomicAdd(&stats[cidx], ls[threadIdx.x]);
        atomicAdd(&stats[C + cidx], ls2[threadIdx.x]);
    }
}

// BN normalize + emit fp16 xh (no relu) + t = bn@U + zh slice (relu, fp16)
template <int C>
__global__ __launch_bounds__(256) void bn_norm_prep_kernel(const float* __restrict__ a,
                                                           const float* __restrict__ stats,
                                                           const float* __restrict__ g,
                                                           const float* __restrict__ be,
                                                           const float* __restrict__ U,
                                                           _Float16* __restrict__ xh,
                                                           float* __restrict__ t,
                                                           _Float16* __restrict__ zh,
                                                           int zoff) {
    __shared__ float mS[C], sS[C], beS[C], Us[C * 4];
    if (threadIdx.x < C) {
        int c = threadIdx.x;
        float mean = stats[c] * (1.f / NN);
        float var = stats[C + c] * (1.f / NN) - mean * mean;
        mS[c] = mean;
        sS[c] = rsqrtf(fmaxf(var, 0.f) + 1e-5f) * g[c];
        beS[c] = be[c];
    }
    for (int i = threadIdx.x; i < C * 4; i += 256) Us[i] = U[i];
    __syncthreads();
    int n = blockIdx.x * 256 + threadIdx.x;
    if (n >= NN) return;
    const float4* ap = reinterpret_cast<const float4*>(a + (size_t)n * C);
    h8* xo = reinterpret_cast<h8*>(xh + (size_t)n * C);
    h8* zo = reinterpret_cast<h8*>(zh + (size_t)n * 128 + zoff);
    float t0 = 0.f, t1 = 0.f, t2 = 0.f, t3 = 0.f;
#pragma unroll
    for (int q8 = 0; q8 < C / 8; q8++) {
        h8 hv, zv;
#pragma unroll
        for (int q4 = 0; q4 < 2; q4++) {
            int c4 = q8 * 2 + q4;
            float4 v = ap[c4];
            float r0 = (v.x - mS[c4 * 4 + 0]) * sS[c4 * 4 + 0] + beS[c4 * 4 + 0];
            float r1 = (v.y - mS[c4 * 4 + 1]) * sS[c4 * 4 + 1] + beS[c4 * 4 + 1];
            float r2 = (v.z - mS[c4 * 4 + 2]) * sS[c4 * 4 + 2] + beS[c4 * 4 + 2];
            float r3 = (v.w - mS[c4 * 4 + 3]) * sS[c4 * 4 + 3] + beS[c4 * 4 + 3];
            hv[q4 * 4 + 0] = (_Float16)r0; hv[q4 * 4 + 1] = (_Float16)r1;
            hv[q4 * 4 + 2] = (_Float16)r2; hv[q4 * 4 + 3] = (_Float16)r3;
            zv[q4 * 4 + 0] = (_Float16)fmaxf(r0, 0.f); zv[q4 * 4 + 1] = (_Float16)fmaxf(r1, 0.f);
            zv[q4 * 4 + 2] = (_Float16)fmaxf(r2, 0.f); zv[q4 * 4 + 3] = (_Float16)fmaxf(r3, 0.f);
            const float* us;
            us = &Us[(c4 * 4 + 0) * 4];
            t0 = fmaf(r0, us[0], t0); t1 = fmaf(r0, us[1], t1); t2 = fmaf(r0, us[2], t2); t3 = fmaf(r0, us[3], t3);
            us = &Us[(c4 * 4 + 1) * 4];
            t0 = fmaf(r1, us[0], t0); t1 = fmaf(r1, us[1], t1); t2 = fmaf(r1, us[2], t2); t3 = fmaf(r1, us[3], t3);
            us = &Us[(c4 * 4 + 2) * 4];
            t0 = fmaf(r2, us[0], t0); t1 = fmaf(r2, us[1], t1); t2 = fmaf(r2, us[2], t2); t3 = fmaf(r2, us[3], t3);
            us = &Us[(c4 * 4 + 3) * 4];
            t0 = fmaf(r3, us[0], t0); t1 = fmaf(r3, us[1], t1); t2 = fmaf(r3, us[2], t2); t3 = fmaf(r3, us[3], t3);
        }
        xo[q8] = hv;
        zo[q8] = zv;
    }
    reinterpret_cast<float4*>(t)[n] = make_float4(t0, t1, t2, t3);
}

// BN normalize (conv6) -> zh[:, 64:128] = fp16(relu(bn))
template <int C>
__global__ __launch_bounds__(256) void bn_norm_z_kernel(const float* __restrict__ a,
                                                        const float* __restrict__ stats,
                                                        const float* __restrict__ g,
                                                        const float* __restrict__ be,
                                                        _Float16* __restrict__ zh,
                                                        int zoff) {
    __shared__ float mS[C], sS[C], beS[C];
    if (threadIdx.x < C) {
        int c = threadIdx.x;
        float mean = stats[c] * (1.f / NN);
        float var = stats[C + c] * (1.f / NN) - mean * mean;
        mS[c] = mean;
        sS[c] = rsqrtf(fmaxf(var, 0.f) + 1e-5f) * g[c];
        beS[c] = be[c];
    }
    __syncthreads();
    int n = blockIdx.x * 256 + threadIdx.x;
    if (n >= NN) return;
    const float4* ap = reinterpret_cast<const float4*>(a + (size_t)n * C);
    h8* zo = reinterpret_cast<h8*>(zh + (size_t)n * 128 + zoff);
#pragma unroll
    for (int q8 = 0; q8 < C / 8; q8++) {
        h8 zv;
#pragma unroll
        for (int q4 = 0; q4 < 2; q4++) {
            int c4 = q8 * 2 + q4;
            float4 v = ap[c4];
            zv[q4 * 4 + 0] = (_Float16)fmaxf((v.x - mS[c4 * 4 + 0]) * sS[c4 * 4 + 0] + beS[c4 * 4 + 0], 0.f);
            zv[q4 * 4 + 1] = (_Float16)fmaxf((v.y - mS[c4 * 4 + 1]) * sS[c4 * 4 + 1] + beS[c4 * 4 + 1], 0.f);
            zv[q4 * 4 + 2] = (_Float16)fmaxf((v.z - mS[c4 * 4 + 2]) * sS[c4 * 4 + 2] + beS[c4 * 4 + 2], 0.f);
            zv[q4 * 4 + 3] = (_Float16)fmaxf((v.w - mS[c4 * 4 + 3]) * sS[c4 * 4 + 3] + beS[c4 * 4 + 3], 0.f);
        }
        zo[q8] = zv;
    }
}

// ---------------- final: z3 = relu(z2@lw3+lb3); out = sigmoid(z3@lwo+lbo) ---
__global__ __launch_bounds__(256) void lin3o_kernel(const _Float16* __restrict__ z2,
                                                    const float* __restrict__ lw3,
                                                    const float* __restrict__ lb3,
                                                    const float* __restrict__ lwo,
                                                    const float* __restrict__ lbo,
                                                    float* __restrict__ out) {
    __shared__ float W3s[64 * 16];
    __shared__ float Wos[16];
    __shared__ float b3s[16];
    for (int i = threadIdx.x; i < 64 * 16; i += 256) W3s[i] = lw3[i];
    if (threadIdx.x < 16) { Wos[threadIdx.x] = lwo[threadIdx.x]; b3s[threadIdx.x] = lb3[threadIdx.x]; }
    __syncthreads();
    int n = blockIdx.x * 256 + threadIdx.x;
    if (n >= NN) return;
    float acc[16];
#pragma unroll
    for (int u = 0; u < 16; u++) acc[u] = b3s[u];
    const h8* zp = reinterpret_cast<const h8*>(z2 + (size_t)n * 64);
#pragma unroll
    for (int k8 = 0; k8 < 8; k8++) {
        h8 v = zp[k8];
#pragma unroll
        for (int u = 0; u < 8; u++) {
            float vf = (float)v[u];
            const float* w = &W3s[(k8 * 8 + u) * 16];
#pragma unroll
            for (int o = 0; o < 16; o++) acc[o] = fmaf(vf, w[o], acc[o]);
        }
    }
    float s = lbo[0];
#pragma unroll
    for (int u = 0; u < 16; u++) s = fmaf(fmaxf(acc[u], 0.f), Wos[u], s);
    out[n] = 1.f / (1.f + __expf(-s));
}

// ------------------------------- launcher -----------------------------------
extern "C" void kernel_launch(void* const* d_in, const int* in_sizes, int n_in,
                              void* d_out, int out_size, void* d_ws, size_t ws_size,
                              hipStream_t stream) {
    const float* x = (const float*)d_in[0];
    const int* ei = (const int*)d_in[1];
    const int* esrc = ei;
    const int* edst = ei + NE;
    const float* W[6]; const float* U[6]; const float* C[6]; const float* B[6];
    for (int i = 0; i < 6; i++) {
        W[i] = (const float*)d_in[2 + 4 * i];
        U[i] = (const float*)d_in[3 + 4 * i];
        C[i] = (const float*)d_in[4 + 4 * i];
        B[i] = (const float*)d_in[5 + 4 * i];
    }
    const float* g1 = (const float*)d_in[26]; const float* be1 = (const float*)d_in[27];
    const float* g2 = (const float*)d_in[28]; const float* be2 = (const float*)d_in[29];
    const float* g3 = (const float*)d_in[30]; const float* be3 = (const float*)d_in[31];
    const float* lw1 = (const float*)d_in[32]; const float* lb1 = (const float*)d_in[33];
    const float* lw2 = (const float*)d_in[34]; const float* lb2 = (const float*)d_in[35];
    const float* lw3 = (const float*)d_in[36]; const float* lb3 = (const float*)d_in[37];
    const float* lwo = (const float*)d_in[38]; const float* lbo = (const float*)d_in[39];

    char* w = (char*)d_ws;
    size_t o = 0;
    auto take = [&](size_t bytes) -> char* {
        char* p = w + o;
        o = (o + bytes + 255) & ~(size_t)255;
        return p;
    };
    int* deg = (int*)take((size_t)NN * 4);
    float* stats = (float*)take(3 * 256 * 4);
    size_t zero_bytes = o;                    // deg + stats zeroed
    int* fillc = (int*)take((size_t)NN * 4);  // init by scan_final
    int* row_ptr = (int*)take((size_t)(NN + 1) * 4);
    int* bsum = (int*)take((size_t)(SNB + 1) * 4);
    int* bpre = (int*)take((size_t)(SNB + 1) * 4);
    int* colA = (int*)take((size_t)NE * 4);
    float* t = (float*)take((size_t)NN * 4 * 4);
    _Float16* xh = (_Float16*)take((size_t)NN * 32 * 2);
    char* A = take((size_t)NN * 256 * 2);     // y fp16 [N,128] then z1h fp16 [N,256]
    _Float16* y = (_Float16*)A;
    _Float16* z1h = (_Float16*)A;
    _Float16* zh = (_Float16*)take((size_t)NN * 128 * 2);
    float* tmp = (float*)take((size_t)NN * 64 * 4);
    _Float16* z2h = (_Float16*)tmp;           // tmp free after bn3
    float* st0 = stats, *st1 = stats + 256, *st2 = stats + 512;

    hipMemsetAsync(d_ws, 0, zero_bytes, stream);

    const int EB = (NE + 255) / 256;
    const int NB = (NN + 255) / 256;
    const int GB = 250;                        // mfma grid.x

    hist_kernel<<<EB, 256, 0, stream>>>(edst, deg);
    scan_bsum_kernel<<<SNB, 256, 0, stream>>>(deg, bsum);
    scan_tops_kernel<<<1, 256, 0, stream>>>(bsum, bpre);
    scan_final_kernel<<<SNB, 256, 0, stream>>>(deg, bpre, row_ptr, fillc);
    fill_kernel<<<EB, 256, 0, stream>>>(esrc, edst, fillc, colA);

    // conv1: 16 -> 16 (mfma emits xh + t via fused epilogue)
    prep_kernel<16><<<NB, 256, 0, stream>>>(x, U[0], xh, t);
    aggD_kernel<16><<<NN, 128, 0, stream>>>(xh, t, C[0], row_ptr, colA, y);
    mfma_dense_kernel<64, 16, 16, true, true, true><<<dim3(GB, 1), 256, 0, stream>>>(y, W[0], B[0], U[1], xh, t);
    // conv2: 16 -> 32, BN1 -> xh/t/zh[:,0:32]
    aggD_kernel<16><<<NN, 128, 0, stream>>>(xh, t, C[1], row_ptr, colA, y);
    mfma_dense_kernel<64, 32, 32, true, false, false><<<dim3(GB, 1), 256, 0, stream>>>(y, W[1], B[1], nullptr, tmp, nullptr);
    bn_reduce_kernel<32><<<256, 256, 0, stream>>>(tmp, st0);
    bn_norm_prep_kernel<32><<<NB, 256, 0, stream>>>(tmp, st0, g1, be1, U[2], xh, t, zh, 0);
    // conv3: 32 -> 32
    aggD_kernel<32><<<NN, 128, 0, stream>>>(xh, t, C[2], row_ptr, colA, y);
    mfma_dense_kernel<128, 32, 32, true, true, true><<<dim3(GB, 1), 256, 0, stream>>>(y, W[2], B[2], U[3], xh, t);
    // conv4: 32 -> 32, BN2 -> xh/t/zh[:,32:64]
    aggD_kernel<32><<<NN, 128, 0, stream>>>(xh, t, C[3], row_ptr, colA, y);
    mfma_dense_kernel<128, 32, 32, true, false, false><<<dim3(GB, 1), 256, 0, stream>>>(y, W[3], B[3], nullptr, tmp, nullptr);
    bn_reduce_kernel<32><<<256, 256, 0, stream>>>(tmp, st1);
    bn_norm_prep_kernel<32><<<NB, 256, 0, stream>>>(tmp, st1, g2, be2, U[4], xh, t, zh, 32);
    // conv5: 32 -> 32
    aggD_kernel<32><<<NN, 128, 0, stream>>>(xh, t, C[4], row_ptr, colA, y);
    mfma_dense_kernel<128, 32, 32, true, true, true><<<dim3(GB, 1), 256, 0, stream>>>(y, W[4], B[4], U[5], xh, t);
    // conv6: 32 -> 64, BN3 -> zh[:,64:128]
    aggD_kernel<32><<<NN, 128, 0, stream>>>(xh, t, C[5], row_ptr, colA, y);
    mfma_dense_kernel<128, 64, 64, true, false, false><<<dim3(GB, 1), 256, 0, stream>>>(y, W[5], B[5], nullptr, tmp, nullptr);
    bn_reduce_kernel<64><<<256, 256, 0, stream>>>(tmp, st2);
    bn_norm_z_kernel<64><<<NB, 256, 0, stream>>>(tmp, st2, g3, be3, zh, 64);

    // MLP head
    mfma_dense_kernel<128, 256, 64, false, true, false><<<dim3(GB, 4), 256, 0, stream>>>(zh, lw1, lb1, nullptr, z1h, nullptr);
    mfma_dense_kernel<256, 64, 64, false, true, false><<<dim3(GB, 1), 256, 0, stream>>>(z1h, lw2, lb2, nullptr, z2h, nullptr);
    lin3o_kernel<<<NB, 256, 0, stream>>>(z2h, lw3, lb3, lwo, lbo, (float*)d_out);
}

// Round 10
// 579.642 us; speedup vs baseline: 1.1992x; 1.0794x over previous
//
#include <hip/hip_runtime.h>

constexpr int NN = 50000;   // nodes
constexpr int NE = 800000;  // edges (without self loops)
constexpr int SNB = (NN + 255) / 256;  // scan blocks = 196

typedef _Float16 h8 __attribute__((ext_vector_type(8)));
typedef _Float16 h4v __attribute__((ext_vector_type(4)));
typedef float f32x4 __attribute__((ext_vector_type(4)));

// ----------------------------- CSR build -----------------------------------
__global__ void hist_kernel(const int* __restrict__ dst, int* __restrict__ deg) {
    int e = blockIdx.x * blockDim.x + threadIdx.x;
    if (e < NE) atomicAdd(&deg[dst[e]], 1);
}

__global__ __launch_bounds__(256) void scan_bsum_kernel(const int* __restrict__ deg,
                                                        int* __restrict__ bsum) {
    int i = blockIdx.x * 256 + threadIdx.x;
    int v = (i < NN) ? deg[i] : 0;
#pragma unroll
    for (int off = 32; off > 0; off >>= 1) v += __shfl_xor(v, off);
    __shared__ int ws[4];
    if ((threadIdx.x & 63) == 0) ws[threadIdx.x >> 6] = v;
    __syncthreads();
    if (threadIdx.x == 0) bsum[blockIdx.x] = ws[0] + ws[1] + ws[2] + ws[3];
}

__global__ __launch_bounds__(256) void scan_tops_kernel(const int* __restrict__ bsum,
                                                        int* __restrict__ bpre) {
    int tid = threadIdx.x;
    int v = (tid < SNB) ? bsum[tid] : 0;
    int lane = tid & 63, wid = tid >> 6;
    int x = v;
#pragma unroll
    for (int off = 1; off < 64; off <<= 1) {
        int y = __shfl_up(x, off, 64);
        if (lane >= off) x += y;
    }
    __shared__ int wsum[4];
    if (lane == 63) wsum[wid] = x;
    __syncthreads();
    int wpre = 0;
    for (int w = 0; w < wid; w++) wpre += wsum[w];
    if (tid < SNB) bpre[tid] = wpre + x - v;  // exclusive
    if (tid == 0) bpre[SNB] = wsum[0] + wsum[1] + wsum[2] + wsum[3];
}

__global__ __launch_bounds__(256) void scan_final_kernel(const int* __restrict__ deg,
                                                         const int* __restrict__ bpre,
                                                         int* __restrict__ row_ptr,
                                                         int* __restrict__ fillc) {
    int i = blockIdx.x * 256 + threadIdx.x;
    int v = (i < NN) ? deg[i] : 0;
    int lane = threadIdx.x & 63, wid = threadIdx.x >> 6;
    int x = v;
#pragma unroll
    for (int off = 1; off < 64; off <<= 1) {
        int y = __shfl_up(x, off, 64);
        if (lane >= off) x += y;
    }
    __shared__ int wsum[4];
    if (lane == 63) wsum[wid] = x;
    __syncthreads();
    int wpre = 0;
    for (int w = 0; w < wid; w++) wpre += wsum[w];
    int ex = bpre[blockIdx.x] + wpre + x - v;
    if (i < NN) { row_ptr[i] = ex; fillc[i] = ex; }
    if (i == 0) row_ptr[NN] = bpre[SNB];
}

// fillc pre-initialized to row_ptr -> atomic returns absolute slot
__global__ void fill_kernel(const int* __restrict__ src, const int* __restrict__ dst,
                            int* __restrict__ fillc, int* __restrict__ col) {
    int e = blockIdx.x * blockDim.x + threadIdx.x;
    if (e < NE) {
        int d = dst[e];
        int k = atomicAdd(&fillc[d], 1);
        col[k] = src[e];
    }
}

// -------------- prep (conv1 only): xh = fp16(x), t = x@U --------------------
template <int CI>
__global__ __launch_bounds__(256) void prep_kernel(const float* __restrict__ x,
                                                   const float* __restrict__ U,
                                                   _Float16* __restrict__ xh,
                                                   float* __restrict__ t) {
    __shared__ float Us[CI * 4];
    for (int i = threadIdx.x; i < CI * 4; i += 256) Us[i] = U[i];
    __syncthreads();
    int n = blockIdx.x * 256 + threadIdx.x;
    if (n >= NN) return;
    float xr[CI];
    const float4* xv = reinterpret_cast<const float4*>(x + (size_t)n * CI);
#pragma unroll
    for (int q = 0; q < CI / 4; q++) {
        float4 v = xv[q];
        xr[4 * q + 0] = v.x; xr[4 * q + 1] = v.y; xr[4 * q + 2] = v.z; xr[4 * q + 3] = v.w;
    }
    h8* xo = reinterpret_cast<h8*>(xh + (size_t)n * CI);
#pragma unroll
    for (int q = 0; q < CI / 8; q++) {
        h8 hv;
#pragma unroll
        for (int u = 0; u < 8; u++) hv[u] = (_Float16)xr[8 * q + u];
        xo[q] = hv;
    }
    float a0 = 0.f, a1 = 0.f, a2 = 0.f, a3 = 0.f;
#pragma unroll
    for (int k = 0; k < CI; k++) {
        float xk = xr[k];
        a0 = fmaf(xk, Us[k * 4 + 0], a0); a1 = fmaf(xk, Us[k * 4 + 1], a1);
        a2 = fmaf(xk, Us[k * 4 + 2], a2); a3 = fmaf(xk, Us[k * 4 + 3], a3);
    }
    reinterpret_cast<float4*>(t)[n] = make_float4(a0, a1, a2, a3);
}

// ------- fused aggregation: 1 wave per node; q once per edge via LDS --------
// Phase 1: lane j computes softmax q for edge j (fp32). Phase 2: NSLOT slots
// x CI channels gather xh and FMA. Single wave -> barrier is nearly free.
template <int CI>
__global__ __launch_bounds__(64) void aggD_kernel(const _Float16* __restrict__ xh,
                                                  const float* __restrict__ t,
                                                  const float* __restrict__ cvec,
                                                  const int* __restrict__ row_ptr,
                                                  const int* __restrict__ col,
                                                  _Float16* __restrict__ y) {
    constexpr int NSLOT = 64 / CI;
    __shared__ int ss[64];
    __shared__ float4 qs[64];
    int tid = threadIdx.x;
    int n = blockIdx.x;                  // grid = NN exactly
    int ch = tid & (CI - 1);
    int slot = tid / CI;
    float4 cv = *reinterpret_cast<const float4*>(cvec);
    float4 td = reinterpret_cast<const float4*>(t)[n];
    float b0 = cv.x - td.x, b1 = cv.y - td.y, b2 = cv.z - td.z, b3 = cv.w - td.w;
    float a0 = 0.f, a1 = 0.f, a2 = 0.f, a3 = 0.f;
    if (slot == 0) {   // self loop: q = softmax(c)
        float m = fmaxf(fmaxf(cv.x, cv.y), fmaxf(cv.z, cv.w));
        float s0 = __expf(cv.x - m), s1 = __expf(cv.y - m),
              s2 = __expf(cv.z - m), s3 = __expf(cv.w - m);
        float sinv = 1.f / (s0 + s1 + s2 + s3);
        float xself = (float)xh[(size_t)n * CI + ch];
        a0 = s0 * sinv * xself; a1 = s1 * sinv * xself;
        a2 = s2 * sinv * xself; a3 = s3 * sinv * xself;
    }
    int beg = row_ptr[n], end = row_ptr[n + 1];
    for (int base = beg; base < end; base += 64) {
        int m = end - base;
        if (m > 64) m = 64;
        if (tid < m) {
            int s = col[base + tid];
            float4 ts = reinterpret_cast<const float4*>(t)[s];
            float d0 = ts.x + b0, d1 = ts.y + b1, d2 = ts.z + b2, d3 = ts.w + b3;
            float mm = fmaxf(fmaxf(d0, d1), fmaxf(d2, d3));
            float q0 = __expf(d0 - mm), q1 = __expf(d1 - mm);
            float q2 = __expf(d2 - mm), q3 = __expf(d3 - mm);
            float is = 1.f / (q0 + q1 + q2 + q3);
            ss[tid] = s;
            qs[tid] = make_float4(q0 * is, q1 * is, q2 * is, q3 * is);
        }
        __syncthreads();
#pragma unroll 4
        for (int j = slot; j < m; j += NSLOT) {
            int s = ss[j];                  // LDS broadcast within lane group
            float4 q = qs[j];
            float xv = (float)xh[(size_t)s * CI + ch];
            a0 = fmaf(q.x, xv, a0); a1 = fmaf(q.y, xv, a1);
            a2 = fmaf(q.z, xv, a2); a3 = fmaf(q.w, xv, a3);
        }
        __syncthreads();                    // protect LDS before next chunk
    }
    // combine slots within the wave
#pragma unroll
    for (int off = 32; off >= CI; off >>= 1) {
        a0 += __shfl_xor(a0, off); a1 += __shfl_xor(a1, off);
        a2 += __shfl_xor(a2, off); a3 += __shfl_xor(a3, off);
    }
    if (tid < CI) {
        float sc = 1.f / (float)(end - beg + 1);
        _Float16* yo = y + (size_t)n * 4 * CI + ch;
        yo[0]      = (_Float16)(a0 * sc);
        yo[CI]     = (_Float16)(a1 * sc);
        yo[2 * CI] = (_Float16)(a2 * sc);
        yo[3 * CI] = (_Float16)(a3 * sc);
    }
}

// ---------------- MFMA GEMM: out = relu(A @ B + bias) [+ t = out@U] ---------
// v_mfma_f32_16x16x16f16 fragments: A: row=l&15, k=4*(l>>4)+j
//                                   B: col=l&15, k=4*(l>>4)+j
//                                   C: row=(l>>4)*4+i, col=l&15
template <int K, int CO, int COB, bool STACKED, bool OUT16, bool TPREP>
__global__ __launch_bounds__(256) void mfma_dense_kernel(const _Float16* __restrict__ A,
                                                         const float* __restrict__ W,
                                                         const float* __restrict__ bias,
                                                         const float* __restrict__ U,
                                                         void* __restrict__ outp,
                                                         float* __restrict__ tout) {
    constexpr int KS = K / 16;
    constexpr int OT = COB / 16;
    constexpr int CIc = K / 4;
    __shared__ _Float16 Bf[OT * KS * 64 * 4];
    __shared__ float bS[COB];
    __shared__ float Us[TPREP ? CO * 4 : 4];
    int o0 = blockIdx.y * COB;
    for (int idx = threadIdx.x; idx < OT * KS * 64; idx += 256) {
        int lane = idx & 63;
        int ks = (idx >> 6) % KS;
        int ot = idx / (64 * KS);
        int o = o0 + ot * 16 + (lane & 15);
        int kb = ks * 16 + (lane >> 4) * 4;
        h4v v;
#pragma unroll
        for (int j = 0; j < 4; j++) {
            int k = kb + j;
            float wv;
            if constexpr (STACKED) wv = W[(k % CIc) * (4 * CO) + (k / CIc) * CO + o];
            else                   wv = W[k * CO + o];
            v[j] = (_Float16)wv;
        }
        *reinterpret_cast<h4v*>(&Bf[idx * 4]) = v;
    }
    for (int i = threadIdx.x; i < COB; i += 256) bS[i] = bias[o0 + i];
    if constexpr (TPREP) {
        for (int i = threadIdx.x; i < CO * 4; i += 256) Us[i] = U[i];
    }
    __syncthreads();
    int wid = threadIdx.x >> 6, lane = threadIdx.x & 63;
    int row_in = lane & 15;
    int kgrp = lane >> 4;
    for (int mt = blockIdx.x * 4 + wid; mt < NN / 16; mt += gridDim.x * 4) {
        int m0 = mt * 16;
        f32x4 acc[OT];
#pragma unroll
        for (int t = 0; t < OT; t++) acc[t] = {0.f, 0.f, 0.f, 0.f};
        const _Float16* Ab = A + (size_t)(m0 + row_in) * K + kgrp * 4;
#pragma unroll
        for (int ks = 0; ks < KS; ks++) {
            h4v af = *reinterpret_cast<const h4v*>(Ab + ks * 16);
#pragma unroll
            for (int t = 0; t < OT; t++) {
                h4v bf = *reinterpret_cast<const h4v*>(&Bf[((t * KS + ks) * 64 + lane) * 4]);
                acc[t] = __builtin_amdgcn_mfma_f32_16x16x16f16(af, bf, acc[t], 0, 0, 0);
            }
        }
        int orow0 = m0 + kgrp * 4;
#pragma unroll
        for (int t = 0; t < OT; t++) {
            int colo = o0 + t * 16 + row_in;
            float b = bS[t * 16 + row_in];
#pragma unroll
            for (int i = 0; i < 4; i++) {
                float v = fmaxf(acc[t][i] + b, 0.f);
                acc[t][i] = v;   // keep relu'd value for TPREP epilogue
                if constexpr (OUT16)
                    ((_Float16*)outp)[(size_t)(orow0 + i) * CO + colo] = (_Float16)v;
                else
                    ((float*)outp)[(size_t)(orow0 + i) * CO + colo] = v;
            }
        }
        if constexpr (TPREP) {
            float p[4][4];
#pragma unroll
            for (int i = 0; i < 4; i++)
#pragma unroll
                for (int h = 0; h < 4; h++) p[i][h] = 0.f;
#pragma unroll
            for (int tt = 0; tt < OT; tt++) {
                const float* ur = &Us[(tt * 16 + row_in) * 4];
#pragma unroll
                for (int i = 0; i < 4; i++) {
                    float v = acc[tt][i];
#pragma unroll
                    for (int h = 0; h < 4; h++) p[i][h] = fmaf(v, ur[h], p[i][h]);
                }
            }
#pragma unroll
            for (int mask = 1; mask < 16; mask <<= 1) {
#pragma unroll
                for (int i = 0; i < 4; i++)
#pragma unroll
                    for (int h = 0; h < 4; h++) p[i][h] += __shfl_xor(p[i][h], mask);
            }
            tout[(size_t)(orow0 + (row_in >> 2)) * 4 + (row_in & 3)] = p[row_in >> 2][row_in & 3];
        }
    }
}

// ------------------------------- batch norm ---------------------------------
template <int C>
__global__ __launch_bounds__(256) void bn_reduce_kernel(const float* __restrict__ a,
                                                        float* __restrict__ stats) {
    constexpr int R = 256 / C;
    int cidx = threadIdx.x % C;
    int r = threadIdx.x / C;
    float s = 0.f, s2 = 0.f;
    for (int n = blockIdx.x * R + r; n < NN; n += gridDim.x * R) {
        float v = a[(size_t)n * C + cidx];
        s += v; s2 = fmaf(v, v, s2);
    }
    __shared__ float ls[256], ls2[256];
    ls[threadIdx.x] = s; ls2[threadIdx.x] = s2;
    __syncthreads();
    for (int off = 128; off >= C; off >>= 1) {
        if (threadIdx.x < off) {
            ls[threadIdx.x] += ls[threadIdx.x + off];
            ls2[threadIdx.x] += ls2[threadIdx.x + off];
        }
        __syncthreads();
    }
    if (threadIdx.x < C) {
        atomicAdd(&stats[cidx], ls[threadIdx.x]);
        atomicAdd(&stats[C + cidx], ls2[threadIdx.x]);
    }
}

// BN normalize + emit fp16 xh (no relu) + t = bn@U + zh slice (relu, fp16)
template <int C>
__global__ __launch_bounds__(256) void bn_norm_prep_kernel(const float* __restrict__ a,
                                                           const float* __restrict__ stats,
                                                           const float* __restrict__ g,
                                                           const float* __restrict__ be,
                                                           const float* __restrict__ U,
                                                           _Float16* __restrict__ xh,
                                                           float* __restrict__ t,
                                                           _Float16* __restrict__ zh,
                                                           int zoff) {
    __shared__ float mS[C], sS[C], beS[C], Us[C * 4];
    if (threadIdx.x < C) {
        int c = threadIdx.x;
        float mean = stats[c] * (1.f / NN);
        float var = stats[C + c] * (1.f / NN) - mean * mean;
        mS[c] = mean;
        sS[c] = rsqrtf(fmaxf(var, 0.f) + 1e-5f) * g[c];
        beS[c] = be[c];
    }
    for (int i = threadIdx.x; i < C * 4; i += 256) Us[i] = U[i];
    __syncthreads();
    int n = blockIdx.x * 256 + threadIdx.x;
    if (n >= NN) return;
    const float4* ap = reinterpret_cast<const float4*>(a + (size_t)n * C);
    h8* xo = reinterpret_cast<h8*>(xh + (size_t)n * C);
    h8* zo = reinterpret_cast<h8*>(zh + (size_t)n * 128 + zoff);
    float t0 = 0.f, t1 = 0.f, t2 = 0.f, t3 = 0.f;
#pragma unroll
    for (int q8 = 0; q8 < C / 8; q8++) {
        h8 hv, zv;
#pragma unroll
        for (int q4 = 0; q4 < 2; q4++) {
            int c4 = q8 * 2 + q4;
            float4 v = ap[c4];
            float r0 = (v.x - mS[c4 * 4 + 0]) * sS[c4 * 4 + 0] + beS[c4 * 4 + 0];
            float r1 = (v.y - mS[c4 * 4 + 1]) * sS[c4 * 4 + 1] + beS[c4 * 4 + 1];
            float r2 = (v.z - mS[c4 * 4 + 2]) * sS[c4 * 4 + 2] + beS[c4 * 4 + 2];
            float r3 = (v.w - mS[c4 * 4 + 3]) * sS[c4 * 4 + 3] + beS[c4 * 4 + 3];
            hv[q4 * 4 + 0] = (_Float16)r0; hv[q4 * 4 + 1] = (_Float16)r1;
            hv[q4 * 4 + 2] = (_Float16)r2; hv[q4 * 4 + 3] = (_Float16)r3;
            zv[q4 * 4 + 0] = (_Float16)fmaxf(r0, 0.f); zv[q4 * 4 + 1] = (_Float16)fmaxf(r1, 0.f);
            zv[q4 * 4 + 2] = (_Float16)fmaxf(r2, 0.f); zv[q4 * 4 + 3] = (_Float16)fmaxf(r3, 0.f);
            const float* us;
            us = &Us[(c4 * 4 + 0) * 4];
            t0 = fmaf(r0, us[0], t0); t1 = fmaf(r0, us[1], t1); t2 = fmaf(r0, us[2], t2); t3 = fmaf(r0, us[3], t3);
            us = &Us[(c4 * 4 + 1) * 4];
            t0 = fmaf(r1, us[0], t0); t1 = fmaf(r1, us[1], t1); t2 = fmaf(r1, us[2], t2); t3 = fmaf(r1, us[3], t3);
            us = &Us[(c4 * 4 + 2) * 4];
            t0 = fmaf(r2, us[0], t0); t1 = fmaf(r2, us[1], t1); t2 = fmaf(r2, us[2], t2); t3 = fmaf(r2, us[3], t3);
            us = &Us[(c4 * 4 + 3) * 4];
            t0 = fmaf(r3, us[0], t0); t1 = fmaf(r3, us[1], t1); t2 = fmaf(r3, us[2], t2); t3 = fmaf(r3, us[3], t3);
        }
        xo[q8] = hv;
        zo[q8] = zv;
    }
    reinterpret_cast<float4*>(t)[n] = make_float4(t0, t1, t2, t3);
}

// BN normalize (conv6) -> zh[:, 64:128] = fp16(relu(bn))
template <int C>
__global__ __launch_bounds__(256) void bn_norm_z_kernel(const float* __restrict__ a,
                                                        const float* __restrict__ stats,
                                                        const float* __restrict__ g,
                                                        const float* __restrict__ be,
                                                        _Float16* __restrict__ zh,
                                                        int zoff) {
    __shared__ float mS[C], sS[C], beS[C];
    if (threadIdx.x < C) {
        int c = threadIdx.x;
        float mean = stats[c] * (1.f / NN);
        float var = stats[C + c] * (1.f / NN) - mean * mean;
        mS[c] = mean;
        sS[c] = rsqrtf(fmaxf(var, 0.f) + 1e-5f) * g[c];
        beS[c] = be[c];
    }
    __syncthreads();
    int n = blockIdx.x * 256 + threadIdx.x;
    if (n >= NN) return;
    const float4* ap = reinterpret_cast<const float4*>(a + (size_t)n * C);
    h8* zo = reinterpret_cast<h8*>(zh + (size_t)n * 128 + zoff);
#pragma unroll
    for (int q8 = 0; q8 < C / 8; q8++) {
        h8 zv;
#pragma unroll
        for (int q4 = 0; q4 < 2; q4++) {
            int c4 = q8 * 2 + q4;
            float4 v = ap[c4];
            zv[q4 * 4 + 0] = (_Float16)fmaxf((v.x - mS[c4 * 4 + 0]) * sS[c4 * 4 + 0] + beS[c4 * 4 + 0], 0.f);
            zv[q4 * 4 + 1] = (_Float16)fmaxf((v.y - mS[c4 * 4 + 1]) * sS[c4 * 4 + 1] + beS[c4 * 4 + 1], 0.f);
            zv[q4 * 4 + 2] = (_Float16)fmaxf((v.z - mS[c4 * 4 + 2]) * sS[c4 * 4 + 2] + beS[c4 * 4 + 2], 0.f);
            zv[q4 * 4 + 3] = (_Float16)fmaxf((v.w - mS[c4 * 4 + 3]) * sS[c4 * 4 + 3] + beS[c4 * 4 + 3], 0.f);
        }
        zo[q8] = zv;
    }
}

// ---------------- final: z3 = relu(z2@lw3+lb3); out = sigmoid(z3@lwo+lbo) ---
__global__ __launch_bounds__(256) void lin3o_kernel(const _Float16* __restrict__ z2,
                                                    const float* __restrict__ lw3,
                                                    const float* __restrict__ lb3,
                                                    const float* __restrict__ lwo,
                                                    const float* __restrict__ lbo,
                                                    float* __restrict__ out) {
    __shared__ float W3s[64 * 16];
    __shared__ float Wos[16];
    __shared__ float b3s[16];
    for (int i = threadIdx.x; i < 64 * 16; i += 256) W3s[i] = lw3[i];
    if (threadIdx.x < 16) { Wos[threadIdx.x] = lwo[threadIdx.x]; b3s[threadIdx.x] = lb3[threadIdx.x]; }
    __syncthreads();
    int n = blockIdx.x * 256 + threadIdx.x;
    if (n >= NN) return;
    float acc[16];
#pragma unroll
    for (int u = 0; u < 16; u++) acc[u] = b3s[u];
    const h8* zp = reinterpret_cast<const h8*>(z2 + (size_t)n * 64);
#pragma unroll
    for (int k8 = 0; k8 < 8; k8++) {
        h8 v = zp[k8];
#pragma unroll
        for (int u = 0; u < 8; u++) {
            float vf = (float)v[u];
            const float* w = &W3s[(k8 * 8 + u) * 16];
#pragma unroll
            for (int o = 0; o < 16; o++) acc[o] = fmaf(vf, w[o], acc[o]);
        }
    }
    float s = lbo[0];
#pragma unroll
    for (int u = 0; u < 16; u++) s = fmaf(fmaxf(acc[u], 0.f), Wos[u], s);
    out[n] = 1.f / (1.f + __expf(-s));
}

// ------------------------------- launcher -----------------------------------
extern "C" void kernel_launch(void* const* d_in, const int* in_sizes, int n_in,
                              void* d_out, int out_size, void* d_ws, size_t ws_size,
                              hipStream_t stream) {
    const float* x = (const float*)d_in[0];
    const int* ei = (const int*)d_in[1];
    const int* esrc = ei;
    const int* edst = ei + NE;
    const float* W[6]; const float* U[6]; const float* C[6]; const float* B[6];
    for (int i = 0; i < 6; i++) {
        W[i] = (const float*)d_in[2 + 4 * i];
        U[i] = (const float*)d_in[3 + 4 * i];
        C[i] = (const float*)d_in[4 + 4 * i];
        B[i] = (const float*)d_in[5 + 4 * i];
    }
    const float* g1 = (const float*)d_in[26]; const float* be1 = (const float*)d_in[27];
    const float* g2 = (const float*)d_in[28]; const float* be2 = (const float*)d_in[29];
    const float* g3 = (const float*)d_in[30]; const float* be3 = (const float*)d_in[31];
    const float* lw1 = (const float*)d_in[32]; const float* lb1 = (const float*)d_in[33];
    const float* lw2 = (const float*)d_in[34]; const float* lb2 = (const float*)d_in[35];
    const float* lw3 = (const float*)d_in[36]; const float* lb3 = (const float*)d_in[37];
    const float* lwo = (const float*)d_in[38]; const float* lbo = (const float*)d_in[39];

    char* w = (char*)d_ws;
    size_t o = 0;
    auto take = [&](size_t bytes) -> char* {
        char* p = w + o;
        o = (o + bytes + 255) & ~(size_t)255;
        return p;
    };
    int* deg = (int*)take((size_t)NN * 4);
    float* stats = (float*)take(3 * 256 * 4);
    size_t zero_bytes = o;                    // deg + stats zeroed
    int* fillc = (int*)take((size_t)NN * 4);  // init by scan_final
    int* row_ptr = (int*)take((size_t)(NN + 1) * 4);
    int* bsum = (int*)take((size_t)(SNB + 1) * 4);
    int* bpre = (int*)take((size_t)(SNB + 1) * 4);
    int* colA = (int*)take((size_t)NE * 4);
    float* t = (float*)take((size_t)NN * 4 * 4);
    _Float16* xh = (_Float16*)take((size_t)NN * 32 * 2);
    char* A = take((size_t)NN * 256 * 2);     // y fp16 [N,128] then z1h fp16 [N,256]
    _Float16* y = (_Float16*)A;
    _Float16* z1h = (_Float16*)A;
    _Float16* zh = (_Float16*)take((size_t)NN * 128 * 2);
    float* tmp = (float*)take((size_t)NN * 64 * 4);
    _Float16* z2h = (_Float16*)tmp;           // tmp free after bn3
    float* st0 = stats, *st1 = stats + 256, *st2 = stats + 512;

    hipMemsetAsync(d_ws, 0, zero_bytes, stream);

    const int EB = (NE + 255) / 256;
    const int NB = (NN + 255) / 256;
    const int GB = 250;                        // mfma grid.x

    hist_kernel<<<EB, 256, 0, stream>>>(edst, deg);
    scan_bsum_kernel<<<SNB, 256, 0, stream>>>(deg, bsum);
    scan_tops_kernel<<<1, 256, 0, stream>>>(bsum, bpre);
    scan_final_kernel<<<SNB, 256, 0, stream>>>(deg, bpre, row_ptr, fillc);
    fill_kernel<<<EB, 256, 0, stream>>>(esrc, edst, fillc, colA);

    // conv1: 16 -> 16 (mfma emits xh + t via fused epilogue)
    prep_kernel<16><<<NB, 256, 0, stream>>>(x, U[0], xh, t);
    aggD_kernel<16><<<NN, 64, 0, stream>>>(xh, t, C[0], row_ptr, colA, y);
    mfma_dense_kernel<64, 16, 16, true, true, true><<<dim3(GB, 1), 256, 0, stream>>>(y, W[0], B[0], U[1], xh, t);
    // conv2: 16 -> 32, BN1 -> xh/t/zh[:,0:32]
    aggD_kernel<16><<<NN, 64, 0, stream>>>(xh, t, C[1], row_ptr, colA, y);
    mfma_dense_kernel<64, 32, 32, true, false, false><<<dim3(GB, 1), 256, 0, stream>>>(y, W[1], B[1], nullptr, tmp, nullptr);
    bn_reduce_kernel<32><<<256, 256, 0, stream>>>(tmp, st0);
    bn_norm_prep_kernel<32><<<NB, 256, 0, stream>>>(tmp, st0, g1, be1, U[2], xh, t, zh, 0);
    // conv3: 32 -> 32
    aggD_kernel<32><<<NN, 64, 0, stream>>>(xh, t, C[2], row_ptr, colA, y);
    mfma_dense_kernel<128, 32, 32, true, true, true><<<dim3(GB, 1), 256, 0, stream>>>(y, W[2], B[2], U[3], xh, t);
    // conv4: 32 -> 32, BN2 -> xh/t/zh[:,32:64]
    aggD_kernel<32><<<NN, 64, 0, stream>>>(xh, t, C[3], row_ptr, colA, y);
    mfma_dense_kernel<128, 32, 32, true, false, false><<<dim3(GB, 1), 256, 0, stream>>>(y, W[3], B[3], nullptr, tmp, nullptr);
    bn_reduce_kernel<32><<<256, 256, 0, stream>>>(tmp, st1);
    bn_norm_prep_kernel<32><<<NB, 256, 0, stream>>>(tmp, st1, g2, be2, U[4], xh, t, zh, 32);
    // conv5: 32 -> 32
    aggD_kernel<32><<<NN, 64, 0, stream>>>(xh, t, C[4], row_ptr, colA, y);
    mfma_dense_kernel<128, 32, 32, true, true, true><<<dim3(GB, 1), 256, 0, stream>>>(y, W[4], B[4], U[5], xh, t);
    // conv6: 32 -> 64, BN3 -> zh[:,64:128]
    aggD_kernel<32><<<NN, 64, 0, stream>>>(xh, t, C[5], row_ptr, colA, y);
    mfma_dense_kernel<128, 64, 64, true, false, false><<<dim3(GB, 1), 256, 0, stream>>>(y, W[5], B[5], nullptr, tmp, nullptr);
    bn_reduce_kernel<64><<<256, 256, 0, stream>>>(tmp, st2);
    bn_norm_z_kernel<64><<<NB, 256, 0, stream>>>(tmp, st2, g3, be3, zh, 64);

    // MLP head
    mfma_dense_kernel<128, 256, 64, false, true, false><<<dim3(GB, 4), 256, 0, stream>>>(zh, lw1, lb1, nullptr, z1h, nullptr);
    mfma_dense_kernel<256, 64, 64, false, true, false><<<dim3(GB, 1), 256, 0, stream>>>(z1h, lw2, lb2, nullptr, z2h, nullptr);
    lin3o_kernel<<<NB, 256, 0, stream>>>(z2h, lw3, lb3, lwo, lbo, (float*)d_out);
}